// Round 5
// baseline (146.253 us; speedup 1.0000x reference)
//
#include <hip/hip_runtime.h>

// out = 2 * heatmap_loss (offset term cancels: o / stopgrad(o/h) == h).
// heatmap_loss = sum_all(w * huber(pred,gt)) / 16  ->  out = sum/8.

typedef float f4 __attribute__((ext_vector_type(4)));  // native vec: nt-load OK

__device__ __forceinline__ float hterm(float p, float g) {
    float err  = fabsf(p - g);
    float quad = fminf(err, 1.0f);      // clip(err, 0, delta=1)
    float lin  = err - quad;
    float h    = 0.5f * quad * quad + lin;
    float w    = (g != 0.0f) ? 1.5f : 0.6f;
    return w * h;
}

__device__ __forceinline__ float hterm4(f4 p, f4 g) {
    return hterm(p.x, g.x) + hterm(p.y, g.y) + hterm(p.z, g.z) + hterm(p.w, g.w);
}

// One-shot max-MLP: 16 independent nontemporal float4 loads per thread
// (256 B/lane in flight) before any use. Tests whether the ~3.2 TB/s read
// plateau is an L2/L3-allocation artifact (nt bypass) or a HW read ceiling.
#define PER_THREAD 8   // float4s per input per thread

__global__ __launch_bounds__(256) void heatmap_reduce_kernel(
        const f4* __restrict__ pred,
        const f4* __restrict__ gt,
        float* __restrict__ partial, int stride) {
    const int tid = blockIdx.x * 256 + threadIdx.x;

    f4 p[PER_THREAD], g[PER_THREAD];
    #pragma unroll
    for (int j = 0; j < PER_THREAD; ++j)
        p[j] = __builtin_nontemporal_load(&pred[tid + j * stride]);
    #pragma unroll
    for (int j = 0; j < PER_THREAD; ++j)
        g[j] = __builtin_nontemporal_load(&gt[tid + j * stride]);

    float acc = 0.0f;
    #pragma unroll
    for (int j = 0; j < PER_THREAD; ++j)
        acc += hterm4(p[j], g[j]);

    #pragma unroll
    for (int off = 32; off > 0; off >>= 1)
        acc += __shfl_down(acc, off, 64);

    __shared__ float wsum[4];
    int lane = threadIdx.x & 63;
    int wave = threadIdx.x >> 6;
    if (lane == 0) wsum[wave] = acc;
    __syncthreads();

    if (threadIdx.x == 0)
        partial[blockIdx.x] = wsum[0] + wsum[1] + wsum[2] + wsum[3];
}

__global__ __launch_bounds__(256) void finalize_kernel(
        const float* __restrict__ partial, float* __restrict__ out, int nblocks) {
    float s = 0.0f;
    for (int i = threadIdx.x; i < nblocks; i += 256)
        s += partial[i];

    #pragma unroll
    for (int off = 32; off > 0; off >>= 1)
        s += __shfl_down(s, off, 64);

    __shared__ float wsum[4];
    int lane = threadIdx.x & 63;
    int wave = threadIdx.x >> 6;
    if (lane == 0) wsum[wave] = s;
    __syncthreads();

    if (threadIdx.x == 0)
        out[0] = (wsum[0] + wsum[1] + wsum[2] + wsum[3]) * 0.125f;
}

extern "C" void kernel_launch(void* const* d_in, const int* in_sizes, int n_in,
                              void* d_out, int out_size, void* d_ws, size_t ws_size,
                              hipStream_t stream) {
    const float* pred = (const float*)d_in[0];
    const float* gt   = (const float*)d_in[1];
    float* out     = (float*)d_out;
    float* partial = (float*)d_ws;

    int n  = in_sizes[0];        // 2*8*64*128*128 = 16,777,216
    int n4 = n >> 2;             // 4,194,304 float4s

    const int block  = 256;
    const int grid   = n4 / (block * PER_THREAD);   // 2048
    const int stride = grid * block;

    heatmap_reduce_kernel<<<grid, block, 0, stream>>>(
        (const f4*)pred, (const f4*)gt, partial, stride);

    finalize_kernel<<<1, block, 0, stream>>>(partial, out, grid);
}